// Round 3
// baseline (519.215 us; speedup 1.0000x reference)
//
#include <hip/hip_runtime.h>

#define NN 50000
#define NE 800000
#define HF 128

// ---- in-degree mask scatter: mask[dst[e]] = 1 ----
__global__ void mask_scatter_k(const int* __restrict__ dst, float* __restrict__ mask) {
    int i = blockIdx.x * blockDim.x + threadIdx.x;
    if (i < NE) mask[dst[i]] = 1.0f;
}

// ---- per-column sum / sumsq over [M,128] fp32 (training-mode BN stats) ----
__global__ __launch_bounds__(128)
void colstats_k(const float* __restrict__ X, int M,
                float* __restrict__ sum, float* __restrict__ sq) {
    int c = threadIdx.x;
    int rpb = (M + gridDim.x - 1) / gridDim.x;
    int r0 = blockIdx.x * rpb;
    int r1 = r0 + rpb; if (r1 > M) r1 = M;
    float s = 0.f, q = 0.f;
    for (int r = r0; r < r1; ++r) {
        float v = X[(size_t)r * HF + c];
        s += v; q += v * v;
    }
    atomicAdd(&sum[c], s);
    atomicAdd(&sq[c], q);
}

// ---- BN -> per-column scale/shift: y = x*a[c] + s[c] ----
__global__ void bnfin_k(const float* __restrict__ sum, const float* __restrict__ sq,
                        const float* __restrict__ g, const float* __restrict__ beta,
                        float* __restrict__ a, float* __restrict__ s) {
    int c = threadIdx.x;
    float mean = sum[c] * (1.0f / NN);
    float var = sq[c] * (1.0f / NN) - mean * mean;   // biased variance
    float rstd = rsqrtf(var + 1e-5f);
    float ga = g[c] * rstd;
    a[c] = ga;
    s[c] = beta[c] - mean * ga;
}

// ---- GEMM: C[M,128] = epi( op_in(A[M,K]) @ W[K,128] + bias ) ----
// IN_MODE: 0 identity, 1 relu(x*scl[c]+shf[c])  (fused BN+ReLU on the A operand)
// EPI:     0 +bias, 1 relu(+bias), 2 rowmask*(+bias)
template<int IN_MODE, int EPI>
__global__ __launch_bounds__(256)
void gemm_k(const float* __restrict__ A, int M, int K,
            const float* __restrict__ W, const float* __restrict__ bias,
            const float* __restrict__ scl, const float* __restrict__ shf,
            const float* __restrict__ rowmask, float* __restrict__ C) {
    constexpr int MT = 64, KT = 32;
    __shared__ __align__(16) float As[KT][MT + 4];   // [k][row]
    __shared__ __align__(16) float Bs[KT][HF];
    const int tid = threadIdx.x;
    const int tx = tid & 15, ty = tid >> 4;          // 16x16 thread grid
    const int row0 = blockIdx.x * MT;

    float acc[4][8];
#pragma unroll
    for (int i = 0; i < 4; ++i)
#pragma unroll
        for (int j = 0; j < 8; ++j) acc[i][j] = 0.f;

    for (int k0 = 0; k0 < K; k0 += KT) {
        // stage A tile 64x32 (transposed into As[k][row]), float4 along K
#pragma unroll
        for (int l = 0; l < 2; ++l) {
            int idx = tid + 256 * l;                 // 0..511
            int r = idx >> 3;                        // 0..63
            int kq = idx & 7;                        // 4-float chunk along K
            int gr = row0 + r; if (gr > M - 1) gr = M - 1;
            float4 f = *(const float4*)(A + (size_t)gr * K + k0 + kq * 4);
            float v[4] = {f.x, f.y, f.z, f.w};
            if (IN_MODE == 1) {
#pragma unroll
                for (int j = 0; j < 4; ++j) {
                    int c = k0 + kq * 4 + j;
                    float t = v[j] * scl[c] + shf[c];
                    v[j] = t > 0.f ? t : 0.f;
                }
            }
#pragma unroll
            for (int j = 0; j < 4; ++j) As[kq * 4 + j][r] = v[j];
        }
        // stage W tile 32x128, float4 along columns
#pragma unroll
        for (int l = 0; l < 4; ++l) {
            int idx = tid + 256 * l;                 // 0..1023 chunks of 4
            int kr = idx >> 5;                       // 0..31
            int c4 = (idx & 31) * 4;
            *(float4*)&Bs[kr][c4] = *(const float4*)(W + (size_t)(k0 + kr) * HF + c4);
        }
        __syncthreads();
#pragma unroll
        for (int k = 0; k < KT; ++k) {
            float4 av = *(const float4*)&As[k][ty * 4];
            float4 b0 = *(const float4*)&Bs[k][tx * 8];
            float4 b1 = *(const float4*)&Bs[k][tx * 8 + 4];
            float aa[4] = {av.x, av.y, av.z, av.w};
            float bb[8] = {b0.x, b0.y, b0.z, b0.w, b1.x, b1.y, b1.z, b1.w};
#pragma unroll
            for (int i = 0; i < 4; ++i)
#pragma unroll
                for (int j = 0; j < 8; ++j)
                    acc[i][j] = fmaf(aa[i], bb[j], acc[i][j]);
        }
        __syncthreads();
    }
    // epilogue (fp32 store)
    float bvv[8];
#pragma unroll
    for (int j = 0; j < 8; ++j) bvv[j] = bias[tx * 8 + j];
#pragma unroll
    for (int i = 0; i < 4; ++i) {
        int gr = row0 + ty * 4 + i;
        if (gr < M) {
            float rm = (EPI == 2) ? rowmask[gr] : 1.0f;
            float out[8];
#pragma unroll
            for (int j = 0; j < 8; ++j) {
                float t = acc[i][j] + bvv[j];
                if (EPI == 1) t = t > 0.f ? t : 0.f;
                if (EPI == 2) t = t * rm;
                out[j] = t;
            }
            float* cp = C + (size_t)gr * HF + tx * 8;
            *(float4*)cp = make_float4(out[0], out[1], out[2], out[3]);
            *(float4*)(cp + 4) = make_float4(out[4], out[5], out[6], out[7]);
        }
    }
}

extern "C" void kernel_launch(void* const* d_in, const int* in_sizes, int n_in,
                              void* d_out, int out_size, void* d_ws, size_t ws_size,
                              hipStream_t stream) {
    // Reference dtypes: all float tensors are float32; edge_index is int32.
    const float* x   = (const float*)d_in[0];
    const int*   ei  = (const int*)d_in[1];
    const float* W1  = (const float*)d_in[2];
    const float* b1  = (const float*)d_in[3];
    const float* g1  = (const float*)d_in[4];
    const float* be1 = (const float*)d_in[5];
    const float* W2  = (const float*)d_in[6];
    const float* b2  = (const float*)d_in[7];
    const float* g2  = (const float*)d_in[8];
    const float* be2 = (const float*)d_in[9];
    // Wq/bq (10,11) and Wk/bk (12,13) cancel: V is gathered at dst, so
    // segment_sum(attn * V[dst]) = V * (softmax sum) = V for in-degree>0 nodes.
    const float* Wv  = (const float*)d_in[14];
    const float* bv  = (const float*)d_in[15];
    const float* Wo  = (const float*)d_in[16];
    const float* bo  = (const float*)d_in[17];

    float* out = (float*)d_out;                      // [50000,128] fp32

    char* ws = (char*)d_ws;
    float* buf  = (float*)(ws);                      // 50000*128 f32 = 25.6 MB
    float* mask = (float*)(ws + 25600000);           // 200 KB
    float* st   = (float*)(ws + 25800704);           // stats: 12*128 f32
    float *sum1 = st,       *sq1 = st + 128, *sum2 = st + 256, *sq2 = st + 384;
    float *a1   = st + 512, *s1  = st + 640, *a2   = st + 768, *s2  = st + 896;

    hipMemsetAsync(st, 0, 512 * sizeof(float), stream);     // zero BN accumulators
    hipMemsetAsync(mask, 0, NN * sizeof(float), stream);
    mask_scatter_k<<<dim3((NE + 255) / 256), dim3(256), 0, stream>>>(ei + NE, mask);

    dim3 gg((NN + 63) / 64), bb(256);
    // encoder layer 1: buf = x @ W1 + b1 (raw; stats next)
    gemm_k<0,0><<<gg, bb, 0, stream>>>(x, NN, 256, W1, b1, nullptr, nullptr, nullptr, buf);
    colstats_k<<<dim3(128), dim3(128), 0, stream>>>(buf, NN, sum1, sq1);
    bnfin_k<<<dim3(1), dim3(128), 0, stream>>>(sum1, sq1, g1, be1, a1, s1);
    // encoder layer 2: out = relu(BN(buf)) @ W2 + b2   (d_out used as ping-pong buffer)
    gemm_k<1,0><<<gg, bb, 0, stream>>>(buf, NN, 128, W2, b2, a1, s1, nullptr, out);
    colstats_k<<<dim3(128), dim3(128), 0, stream>>>(out, NN, sum2, sq2);
    bnfin_k<<<dim3(1), dim3(128), 0, stream>>>(sum2, sq2, g2, be2, a2, s2);
    // attn layer 0 (collapsed): buf = mask * (relu(BN(out)) @ Wv0 + bv0)
    gemm_k<1,2><<<gg, bb, 0, stream>>>(out, NN, 128, Wv, bv, a2, s2, mask, buf);
    //                          out = relu(buf @ Wo0 + bo0)
    gemm_k<0,1><<<gg, bb, 0, stream>>>(buf, NN, 128, Wo, bo, nullptr, nullptr, nullptr, out);
    // attn layer 1: buf = mask * (out @ Wv1 + bv1)
    gemm_k<0,2><<<gg, bb, 0, stream>>>(out, NN, 128, Wv + 128 * 128, bv + 128,
                                       nullptr, nullptr, mask, buf);
    //              out = relu(buf @ Wo1 + bo1)
    gemm_k<0,1><<<gg, bb, 0, stream>>>(buf, NN, 128, Wo + 128 * 128, bo + 128,
                                       nullptr, nullptr, nullptr, out);
}

// Round 4
// 367.643 us; speedup vs baseline: 1.4123x; 1.4123x over previous
//
#include <hip/hip_runtime.h>

#define NN 50000
#define NE 800000

// ---- in-degree mask scatter: mask[dst[e]] = 1 ----
__global__ void mask_scatter_k(const int* __restrict__ dst, float* __restrict__ mask) {
    int i = blockIdx.x * blockDim.x + threadIdx.x;
    if (i < NE) mask[dst[i]] = 1.0f;
}

// ---- GEMM: C[M,128] = op_in(A[M,K]) @ W[K,128] + bias ----
// FOLD_BN: A-operand transform relu(x*scl+shf), scl/shf computed in-block from
//          (fsum,fsq,fg,fbe) global stats of the PREVIOUS layer (complete by dispatch order).
// STATS:   fused per-column sum/sumsq of the raw output -> global atomics (osum,osq).
template<int FOLD_BN, int STATS>
__global__ __launch_bounds__(256)
void gemm_k(const float* __restrict__ A, int M, int K,
            const float* __restrict__ W, const float* __restrict__ bias,
            const float* __restrict__ fsum, const float* __restrict__ fsq,
            const float* __restrict__ fg, const float* __restrict__ fbe,
            float* __restrict__ osum, float* __restrict__ osq,
            float* __restrict__ C) {
    constexpr int MT = 64, KT = 32;
    __shared__ __align__(16) float As[KT][MT + 4];
    __shared__ __align__(16) float Bs[KT][128];
    __shared__ float scl[128], shf[128];
    __shared__ float lsum[128], lsq[128];
    const int tid = threadIdx.x;
    const int tx = tid & 15, ty = tid >> 4;
    const int row0 = blockIdx.x * MT;

    if (FOLD_BN && tid < 128) {
        float mean = fsum[tid] * (1.0f / NN);
        float var = fsq[tid] * (1.0f / NN) - mean * mean;   // biased
        float rstd = rsqrtf(var + 1e-5f);
        float ga = fg[tid] * rstd;
        scl[tid] = ga;
        shf[tid] = fbe[tid] - mean * ga;
    }
    if (STATS && tid < 128) { lsum[tid] = 0.f; lsq[tid] = 0.f; }
    if (FOLD_BN) __syncthreads();

    float acc[4][8];
#pragma unroll
    for (int i = 0; i < 4; ++i)
#pragma unroll
        for (int j = 0; j < 8; ++j) acc[i][j] = 0.f;

    for (int k0 = 0; k0 < K; k0 += KT) {
#pragma unroll
        for (int l = 0; l < 2; ++l) {
            int idx = tid + 256 * l;
            int r = idx >> 3;
            int kq = idx & 7;
            int gr = row0 + r; if (gr > M - 1) gr = M - 1;
            float4 f = *(const float4*)(A + (size_t)gr * K + k0 + kq * 4);
            float v[4] = {f.x, f.y, f.z, f.w};
            if (FOLD_BN) {
#pragma unroll
                for (int j = 0; j < 4; ++j) {
                    int c = k0 + kq * 4 + j;
                    float t = v[j] * scl[c] + shf[c];
                    v[j] = t > 0.f ? t : 0.f;
                }
            }
#pragma unroll
            for (int j = 0; j < 4; ++j) As[kq * 4 + j][r] = v[j];
        }
#pragma unroll
        for (int l = 0; l < 4; ++l) {
            int idx = tid + 256 * l;
            int kr = idx >> 5;
            int c4 = (idx & 31) * 4;
            *(float4*)&Bs[kr][c4] = *(const float4*)(W + (size_t)(k0 + kr) * 128 + c4);
        }
        __syncthreads();
#pragma unroll
        for (int k = 0; k < KT; ++k) {
            float4 av = *(const float4*)&As[k][ty * 4];
            float4 b0 = *(const float4*)&Bs[k][tx * 8];
            float4 b1 = *(const float4*)&Bs[k][tx * 8 + 4];
            float aa[4] = {av.x, av.y, av.z, av.w};
            float bb[8] = {b0.x, b0.y, b0.z, b0.w, b1.x, b1.y, b1.z, b1.w};
#pragma unroll
            for (int i = 0; i < 4; ++i)
#pragma unroll
                for (int j = 0; j < 8; ++j)
                    acc[i][j] = fmaf(aa[i], bb[j], acc[i][j]);
        }
        __syncthreads();
    }

    float bvv[8];
#pragma unroll
    for (int j = 0; j < 8; ++j) bvv[j] = bias[tx * 8 + j];
    float ps[8], pq[8];
#pragma unroll
    for (int j = 0; j < 8; ++j) { ps[j] = 0.f; pq[j] = 0.f; }
#pragma unroll
    for (int i = 0; i < 4; ++i) {
        int gr = row0 + ty * 4 + i;
        if (gr < M) {
            float out[8];
#pragma unroll
            for (int j = 0; j < 8; ++j) {
                float t = acc[i][j] + bvv[j];
                out[j] = t;
                if (STATS) { ps[j] += t; pq[j] += t * t; }
            }
            float* cp = C + (size_t)gr * 128 + tx * 8;
            *(float4*)cp = make_float4(out[0], out[1], out[2], out[3]);
            *(float4*)(cp + 4) = make_float4(out[4], out[5], out[6], out[7]);
        }
    }
    if (STATS) {
        // reduce over the 4 ty-slices within each wave (lanes: ty = lane>>4)
#pragma unroll
        for (int j = 0; j < 8; ++j) {
            ps[j] += __shfl_xor(ps[j], 16); ps[j] += __shfl_xor(ps[j], 32);
            pq[j] += __shfl_xor(pq[j], 16); pq[j] += __shfl_xor(pq[j], 32);
        }
        if ((tid & 63) < 16) {
#pragma unroll
            for (int j = 0; j < 8; ++j) {
                atomicAdd(&lsum[tx * 8 + j], ps[j]);
                atomicAdd(&lsq[tx * 8 + j], pq[j]);
            }
        }
        __syncthreads();
        if (tid < 128) {
            atomicAdd(&osum[tid], lsum[tid]);
            atomicAdd(&osq[tid], lsq[tid]);
        }
    }
}

// ---- mega-kernel: the whole post-encoder chain, row-local per 64-row block ----
// X (raw h@W2+b2)  -> bn2+relu -> s0: (.@Wv0+bv0)*mask -> s1: relu(.@Wo0+bo0)
//                              -> s2: (.@Wv1+bv1)*mask -> s3: relu(.@Wo1+bo1) -> out
__global__ __launch_bounds__(256)
void mega_k(const float* __restrict__ X,
            const float* __restrict__ fsum, const float* __restrict__ fsq,
            const float* __restrict__ fg, const float* __restrict__ fbe,
            const float* __restrict__ Wv, const float* __restrict__ bv,
            const float* __restrict__ Wo, const float* __restrict__ bo,
            const float* __restrict__ mask, float* __restrict__ out) {
    __shared__ __align__(16) float Act[128][68];    // [feature][row(64)+pad] 34.8 KB
    __shared__ __align__(16) float Bs[32][128];     // 16 KB weight K-chunk
    __shared__ float scl[128], shf[128];
    const int tid = threadIdx.x;
    const int tx = tid & 15, ty = tid >> 4;
    const int row0 = blockIdx.x * 64;

    if (tid < 128) {
        float mean = fsum[tid] * (1.0f / NN);
        float var = fsq[tid] * (1.0f / NN) - mean * mean;
        float rstd = rsqrtf(var + 1e-5f);
        float ga = fg[tid] * rstd;
        scl[tid] = ga;
        shf[tid] = fbe[tid] - mean * ga;
    }
    __syncthreads();

    // row mask (softmax-collapse: nodes w/o incoming edges output bias-only path -> mask 0)
    float rm[4];
#pragma unroll
    for (int i = 0; i < 4; ++i) {
        int gr = row0 + ty * 4 + i;
        rm[i] = (gr < NN) ? mask[gr] : 0.f;
    }

    // load 64 rows of X, apply bn2+relu, store transposed Act[c][r]
    // lane-major rows: conflict-free LDS writes (bank = (4c + r) % 32, r spans the wave)
#pragma unroll
    for (int l = 0; l < 8; ++l) {
        int idx = tid + 256 * l;
        int r = idx & 63;
        int c4 = (idx >> 6) * 4;
        int gr = row0 + r;
        float4 f = (gr < NN) ? *(const float4*)(X + (size_t)gr * 128 + c4)
                             : make_float4(0.f, 0.f, 0.f, 0.f);
        float v[4] = {f.x, f.y, f.z, f.w};
#pragma unroll
        for (int m = 0; m < 4; ++m) {
            float t = v[m] * scl[c4 + m] + shf[c4 + m];
            Act[c4 + m][r] = t > 0.f ? t : 0.f;
        }
    }

    for (int s = 0; s < 4; ++s) {
        const float* Wst; const float* bst;
        if (s == 0)      { Wst = Wv;         bst = bv; }
        else if (s == 1) { Wst = Wo;         bst = bo; }
        else if (s == 2) { Wst = Wv + 16384; bst = bv + 128; }
        else             { Wst = Wo + 16384; bst = bo + 128; }

        float bvv[8];
#pragma unroll
        for (int j = 0; j < 8; ++j) bvv[j] = bst[tx * 8 + j];

        float acc[4][8];
#pragma unroll
        for (int i = 0; i < 4; ++i)
#pragma unroll
            for (int j = 0; j < 8; ++j) acc[i][j] = 0.f;

        for (int k0 = 0; k0 < 128; k0 += 32) {
#pragma unroll
            for (int l = 0; l < 4; ++l) {
                int idx = tid + 256 * l;
                int kr = idx >> 5;
                int c4 = (idx & 31) * 4;
                *(float4*)&Bs[kr][c4] = *(const float4*)(Wst + (size_t)(k0 + kr) * 128 + c4);
            }
            __syncthreads();   // Bs ready; also orders Act writes (init / prev stage) before reads
#pragma unroll
            for (int k = 0; k < 32; ++k) {
                float4 av = *(const float4*)&Act[k0 + k][ty * 4];
                float4 b0 = *(const float4*)&Bs[k][tx * 8];
                float4 b1 = *(const float4*)&Bs[k][tx * 8 + 4];
                float aa[4] = {av.x, av.y, av.z, av.w};
                float bb[8] = {b0.x, b0.y, b0.z, b0.w, b1.x, b1.y, b1.z, b1.w};
#pragma unroll
                for (int i = 0; i < 4; ++i)
#pragma unroll
                    for (int j = 0; j < 8; ++j)
                        acc[i][j] = fmaf(aa[i], bb[j], acc[i][j]);
            }
            __syncthreads();   // all reads done before Bs overwrite / Act overwrite
        }

        if (s == 3) {
#pragma unroll
            for (int i = 0; i < 4; ++i) {
                int gr = row0 + ty * 4 + i;
                if (gr < NN) {
                    float o[8];
#pragma unroll
                    for (int j = 0; j < 8; ++j) {
                        float t = acc[i][j] + bvv[j];
                        o[j] = t > 0.f ? t : 0.f;
                    }
                    float* cp = out + (size_t)gr * 128 + tx * 8;
                    *(float4*)cp = make_float4(o[0], o[1], o[2], o[3]);
                    *(float4*)(cp + 4) = make_float4(o[4], o[5], o[6], o[7]);
                }
            }
        } else {
#pragma unroll
            for (int j = 0; j < 8; ++j) {
                float o0, o1, o2, o3;
                if (s == 1) {   // relu epilogue
                    o0 = fmaxf(acc[0][j] + bvv[j], 0.f);
                    o1 = fmaxf(acc[1][j] + bvv[j], 0.f);
                    o2 = fmaxf(acc[2][j] + bvv[j], 0.f);
                    o3 = fmaxf(acc[3][j] + bvv[j], 0.f);
                } else {        // s==0 / s==2: +bias then row mask (no relu on V path)
                    o0 = (acc[0][j] + bvv[j]) * rm[0];
                    o1 = (acc[1][j] + bvv[j]) * rm[1];
                    o2 = (acc[2][j] + bvv[j]) * rm[2];
                    o3 = (acc[3][j] + bvv[j]) * rm[3];
                }
                *(float4*)&Act[tx * 8 + j][ty * 4] = make_float4(o0, o1, o2, o3);
            }
            __syncthreads();   // Act writes visible before next stage's reads
        }
    }
}

extern "C" void kernel_launch(void* const* d_in, const int* in_sizes, int n_in,
                              void* d_out, int out_size, void* d_ws, size_t ws_size,
                              hipStream_t stream) {
    const float* x   = (const float*)d_in[0];
    const int*   ei  = (const int*)d_in[1];
    const float* W1  = (const float*)d_in[2];
    const float* b1  = (const float*)d_in[3];
    const float* g1  = (const float*)d_in[4];
    const float* be1 = (const float*)d_in[5];
    const float* W2  = (const float*)d_in[6];
    const float* b2  = (const float*)d_in[7];
    const float* g2  = (const float*)d_in[8];
    const float* be2 = (const float*)d_in[9];
    // Wq/bq (10,11), Wk/bk (12,13) cancel: V gathered at dst => segment softmax sums to 1.
    const float* Wv  = (const float*)d_in[14];
    const float* bv  = (const float*)d_in[15];
    const float* Wo  = (const float*)d_in[16];
    const float* bo  = (const float*)d_in[17];

    float* out = (float*)d_out;                    // also used as raw-h2 scratch (row-local mega)

    char* ws = (char*)d_ws;
    float* buf  = (float*)(ws);                    // 25.6 MB: raw x@W1+b1
    float* mask = (float*)(ws + 25600000);
    float* st   = (float*)(ws + 25800704);
    float *sum1 = st, *sq1 = st + 128, *sum2 = st + 256, *sq2 = st + 384;

    hipMemsetAsync(st, 0, 512 * sizeof(float), stream);
    hipMemsetAsync(mask, 0, NN * sizeof(float), stream);
    mask_scatter_k<<<dim3((NE + 255) / 256), dim3(256), 0, stream>>>(ei + NE, mask);

    dim3 gg((NN + 63) / 64), bb(256);
    // enc1: buf = x@W1+b1 (raw), fused column stats -> sum1/sq1
    gemm_k<0,1><<<gg, bb, 0, stream>>>(x, NN, 256, W1, b1,
                                       nullptr, nullptr, nullptr, nullptr,
                                       sum1, sq1, buf);
    // enc2: out = relu(bn1(buf))@W2+b2 (raw), fused stats -> sum2/sq2 (bnfin folded in prologue)
    gemm_k<1,1><<<gg, bb, 0, stream>>>(buf, NN, 128, W2, b2,
                                       sum1, sq1, g1, be1,
                                       sum2, sq2, out);
    // whole attention chain in one persistent-tile kernel (bn2 folded; in-place on d_out)
    mega_k<<<gg, bb, 0, stream>>>(out, sum2, sq2, g2, be2, Wv, bv, Wo, bo, mask, out);
}

// Round 5
// 338.061 us; speedup vs baseline: 1.5359x; 1.0875x over previous
//
#include <hip/hip_runtime.h>

#define NN 50000
#define NE 800000

// ---- in-degree mask scatter: mask[dst[e]] = 1 ----
__global__ void mask_scatter_k(const int* __restrict__ dst, float* __restrict__ mask) {
    int i = blockIdx.x * blockDim.x + threadIdx.x;
    if (i < NE) mask[dst[i]] = 1.0f;
}

// ---- GEMM: C[M,128] = op_in(A[M,K]) @ W[K,128] + bias ----
// Thread (tx,ty) owns rows ty*4..+3, cols {tx*4..+3} U {64+tx*4..+3}  (conflict-free LDS)
// FOLD_BN: A-operand transform relu(x*scl+shf) from prev-layer global stats.
// STATS:   fused per-column sum/sumsq of raw output -> global atomics.
template<int FOLD_BN, int STATS>
__global__ __launch_bounds__(256)
void gemm_k(const float* __restrict__ A, int M, int K,
            const float* __restrict__ W, const float* __restrict__ bias,
            const float* __restrict__ fsum, const float* __restrict__ fsq,
            const float* __restrict__ fg, const float* __restrict__ fbe,
            float* __restrict__ osum, float* __restrict__ osq,
            float* __restrict__ C) {
    constexpr int MT = 64, KT = 32;
    __shared__ __align__(16) float As[KT][MT + 4];
    __shared__ __align__(16) float Bs[KT][128];
    __shared__ float scl[128], shf[128];
    __shared__ float lsum[128], lsq[128];
    const int tid = threadIdx.x;
    const int tx = tid & 15, ty = tid >> 4;
    const int row0 = blockIdx.x * MT;

    if (FOLD_BN && tid < 128) {
        float mean = fsum[tid] * (1.0f / NN);
        float var = fsq[tid] * (1.0f / NN) - mean * mean;   // biased
        float rstd = rsqrtf(var + 1e-5f);
        float ga = fg[tid] * rstd;
        scl[tid] = ga;
        shf[tid] = fbe[tid] - mean * ga;
    }
    if (STATS && tid < 128) { lsum[tid] = 0.f; lsq[tid] = 0.f; }
    if (FOLD_BN || STATS) __syncthreads();

    float acc[4][8];
#pragma unroll
    for (int i = 0; i < 4; ++i)
#pragma unroll
        for (int j = 0; j < 8; ++j) acc[i][j] = 0.f;

    for (int k0 = 0; k0 < K; k0 += KT) {
#pragma unroll
        for (int l = 0; l < 2; ++l) {
            int idx = tid + 256 * l;
            int r = idx >> 3;
            int kq = idx & 7;
            int gr = row0 + r; if (gr > M - 1) gr = M - 1;
            float4 f = *(const float4*)(A + (size_t)gr * K + k0 + kq * 4);
            float v[4] = {f.x, f.y, f.z, f.w};
            if (FOLD_BN) {
#pragma unroll
                for (int j = 0; j < 4; ++j) {
                    int c = k0 + kq * 4 + j;
                    float t = v[j] * scl[c] + shf[c];
                    v[j] = t > 0.f ? t : 0.f;
                }
            }
#pragma unroll
            for (int j = 0; j < 4; ++j) As[kq * 4 + j][r] = v[j];
        }
#pragma unroll
        for (int l = 0; l < 4; ++l) {
            int idx = tid + 256 * l;
            int kr = idx >> 5;
            int c4 = (idx & 31) * 4;
            *(float4*)&Bs[kr][c4] = *(const float4*)(W + (size_t)(k0 + kr) * 128 + c4);
        }
        __syncthreads();
#pragma unroll
        for (int k = 0; k < KT; ++k) {
            float4 av = *(const float4*)&As[k][ty * 4];
            float4 b0 = *(const float4*)&Bs[k][tx * 4];         // banks 4tx..: conflict-free
            float4 b1 = *(const float4*)&Bs[k][64 + tx * 4];
            float aa[4] = {av.x, av.y, av.z, av.w};
            float bb[8] = {b0.x, b0.y, b0.z, b0.w, b1.x, b1.y, b1.z, b1.w};
#pragma unroll
            for (int i = 0; i < 4; ++i)
#pragma unroll
                for (int j = 0; j < 8; ++j)
                    acc[i][j] = fmaf(aa[i], bb[j], acc[i][j]);
        }
        __syncthreads();
    }

    float bvv[8];
#pragma unroll
    for (int j = 0; j < 8; ++j)
        bvv[j] = bias[(j < 4) ? (tx * 4 + j) : (64 + tx * 4 + j - 4)];
    float ps[8], pq[8];
#pragma unroll
    for (int j = 0; j < 8; ++j) { ps[j] = 0.f; pq[j] = 0.f; }
#pragma unroll
    for (int i = 0; i < 4; ++i) {
        int gr = row0 + ty * 4 + i;
        if (gr < M) {
            float out[8];
#pragma unroll
            for (int j = 0; j < 8; ++j) {
                float t = acc[i][j] + bvv[j];
                out[j] = t;
                if (STATS) { ps[j] += t; pq[j] += t * t; }
            }
            float* cp = C + (size_t)gr * 128;
            *(float4*)(cp + tx * 4) = make_float4(out[0], out[1], out[2], out[3]);
            *(float4*)(cp + 64 + tx * 4) = make_float4(out[4], out[5], out[6], out[7]);
        }
    }
    if (STATS) {
#pragma unroll
        for (int j = 0; j < 8; ++j) {
            ps[j] += __shfl_xor(ps[j], 16); ps[j] += __shfl_xor(ps[j], 32);
            pq[j] += __shfl_xor(pq[j], 16); pq[j] += __shfl_xor(pq[j], 32);
        }
        if ((tid & 63) < 16) {
#pragma unroll
            for (int j = 0; j < 8; ++j) {
                int c = (j < 4) ? (tx * 4 + j) : (64 + tx * 4 + j - 4);
                atomicAdd(&lsum[c], ps[j]);
                atomicAdd(&lsq[c], pq[j]);
            }
        }
        __syncthreads();
        if (tid < 128) {
            atomicAdd(&osum[tid], lsum[tid]);
            atomicAdd(&osq[tid], lsq[tid]);
        }
    }
}

// ---- mega-kernel: whole post-encoder chain, row-local per 64-row block ----
// X (raw h@W2+b2) -> bn2+relu -> s0: (.@Wv0+bv0)*mask -> s1: relu(.@Wo0+bo0)
//                             -> s2: (.@Wv1+bv1)*mask -> s3: relu(.@Wo1+bo1) -> out
__global__ __launch_bounds__(256)
void mega_k(const float* __restrict__ X,
            const float* __restrict__ fsum, const float* __restrict__ fsq,
            const float* __restrict__ fg, const float* __restrict__ fbe,
            const float* __restrict__ Wv, const float* __restrict__ bv,
            const float* __restrict__ Wo, const float* __restrict__ bo,
            const float* __restrict__ mask, float* __restrict__ out) {
    __shared__ __align__(16) float Act[128][68];    // [feature][row]; 272B row = 16B-aligned
    __shared__ __align__(16) float Bs[32][128];
    __shared__ float scl[128], shf[128];
    const int tid = threadIdx.x;
    const int tx = tid & 15, ty = tid >> 4;
    const int row0 = blockIdx.x * 64;

    if (tid < 128) {
        float mean = fsum[tid] * (1.0f / NN);
        float var = fsq[tid] * (1.0f / NN) - mean * mean;
        float rstd = rsqrtf(var + 1e-5f);
        float ga = fg[tid] * rstd;
        scl[tid] = ga;
        shf[tid] = fbe[tid] - mean * ga;
    }
    __syncthreads();

    float rm[4];
#pragma unroll
    for (int i = 0; i < 4; ++i) {
        int gr = row0 + ty * 4 + i;
        rm[i] = (gr < NN) ? mask[gr] : 0.f;
    }

    // load 64 rows of X, bn2+relu, store transposed Act[c][r] (r spans wave: 2-way, free)
#pragma unroll
    for (int l = 0; l < 8; ++l) {
        int idx = tid + 256 * l;
        int r = idx & 63;
        int c4 = (idx >> 6) * 4;
        int gr = row0 + r;
        float4 f = (gr < NN) ? *(const float4*)(X + (size_t)gr * 128 + c4)
                             : make_float4(0.f, 0.f, 0.f, 0.f);
        float v[4] = {f.x, f.y, f.z, f.w};
#pragma unroll
        for (int m = 0; m < 4; ++m) {
            float t = v[m] * scl[c4 + m] + shf[c4 + m];
            Act[c4 + m][r] = t > 0.f ? t : 0.f;
        }
    }

    for (int s = 0; s < 4; ++s) {
        const float* Wst; const float* bst;
        if (s == 0)      { Wst = Wv;         bst = bv; }
        else if (s == 1) { Wst = Wo;         bst = bo; }
        else if (s == 2) { Wst = Wv + 16384; bst = bv + 128; }
        else             { Wst = Wo + 16384; bst = bo + 128; }

        float bvv[8];
#pragma unroll
        for (int j = 0; j < 8; ++j)
            bvv[j] = bst[(j < 4) ? (tx * 4 + j) : (64 + tx * 4 + j - 4)];

        float acc[4][8];
#pragma unroll
        for (int i = 0; i < 4; ++i)
#pragma unroll
            for (int j = 0; j < 8; ++j) acc[i][j] = 0.f;

        for (int k0 = 0; k0 < 128; k0 += 32) {
#pragma unroll
            for (int l = 0; l < 4; ++l) {
                int idx = tid + 256 * l;
                int kr = idx >> 5;
                int c4 = (idx & 31) * 4;
                *(float4*)&Bs[kr][c4] = *(const float4*)(Wst + (size_t)(k0 + kr) * 128 + c4);
            }
            __syncthreads();   // Bs ready; orders Act writes (init/prev stage) before reads
#pragma unroll
            for (int k = 0; k < 32; ++k) {
                float4 av = *(const float4*)&Act[k0 + k][ty * 4];   // 4-addr broadcast
                float4 b0 = *(const float4*)&Bs[k][tx * 4];          // conflict-free
                float4 b1 = *(const float4*)&Bs[k][64 + tx * 4];
                float aa[4] = {av.x, av.y, av.z, av.w};
                float bb[8] = {b0.x, b0.y, b0.z, b0.w, b1.x, b1.y, b1.z, b1.w};
#pragma unroll
                for (int i = 0; i < 4; ++i)
#pragma unroll
                    for (int j = 0; j < 8; ++j)
                        acc[i][j] = fmaf(aa[i], bb[j], acc[i][j]);
            }
            __syncthreads();   // all reads done before Bs/Act overwrite
        }

        if (s == 3) {
#pragma unroll
            for (int i = 0; i < 4; ++i) {
                int gr = row0 + ty * 4 + i;
                if (gr < NN) {
                    float o[8];
#pragma unroll
                    for (int j = 0; j < 8; ++j) o[j] = fmaxf(acc[i][j] + bvv[j], 0.f);
                    float* cp = out + (size_t)gr * 128;
                    *(float4*)(cp + tx * 4) = make_float4(o[0], o[1], o[2], o[3]);
                    *(float4*)(cp + 64 + tx * 4) = make_float4(o[4], o[5], o[6], o[7]);
                }
            }
        } else {
            // transposed write-back: col stride 4*68=272 (bank +16), +4ty tiles all 32
            // banks disjointly -> bandwidth-minimal b128 writes
#pragma unroll
            for (int jj = 0; jj < 4; ++jj) {
                float o[4], p[4];
#pragma unroll
                for (int i = 0; i < 4; ++i) {
                    float t0 = acc[i][jj] + bvv[jj];
                    float t1 = acc[i][4 + jj] + bvv[4 + jj];
                    if (s == 1) { o[i] = fmaxf(t0, 0.f);  p[i] = fmaxf(t1, 0.f); }
                    else        { o[i] = t0 * rm[i];      p[i] = t1 * rm[i]; }
                }
                *(float4*)&Act[tx * 4 + jj][ty * 4]      = make_float4(o[0], o[1], o[2], o[3]);
                *(float4*)&Act[64 + tx * 4 + jj][ty * 4] = make_float4(p[0], p[1], p[2], p[3]);
            }
            __syncthreads();   // Act visible before next stage's reads
        }
    }
}

extern "C" void kernel_launch(void* const* d_in, const int* in_sizes, int n_in,
                              void* d_out, int out_size, void* d_ws, size_t ws_size,
                              hipStream_t stream) {
    const float* x   = (const float*)d_in[0];
    const int*   ei  = (const int*)d_in[1];
    const float* W1  = (const float*)d_in[2];
    const float* b1  = (const float*)d_in[3];
    const float* g1  = (const float*)d_in[4];
    const float* be1 = (const float*)d_in[5];
    const float* W2  = (const float*)d_in[6];
    const float* b2  = (const float*)d_in[7];
    const float* g2  = (const float*)d_in[8];
    const float* be2 = (const float*)d_in[9];
    // Wq/bq (10,11), Wk/bk (12,13) cancel: V gathered at dst => segment softmax sums to 1.
    const float* Wv  = (const float*)d_in[14];
    const float* bv  = (const float*)d_in[15];
    const float* Wo  = (const float*)d_in[16];
    const float* bo  = (const float*)d_in[17];

    float* out = (float*)d_out;

    char* ws = (char*)d_ws;
    float* buf  = (float*)(ws);                    // 25.6 MB: raw x@W1+b1
    float* mask = (float*)(ws + 25600000);
    float* st   = (float*)(ws + 25800704);
    float *sum1 = st, *sq1 = st + 128, *sum2 = st + 256, *sq2 = st + 384;

    hipMemsetAsync(st, 0, 512 * sizeof(float), stream);
    hipMemsetAsync(mask, 0, NN * sizeof(float), stream);
    mask_scatter_k<<<dim3((NE + 255) / 256), dim3(256), 0, stream>>>(ei + NE, mask);

    dim3 gg((NN + 63) / 64), bb(256);
    gemm_k<0,1><<<gg, bb, 0, stream>>>(x, NN, 256, W1, b1,
                                       nullptr, nullptr, nullptr, nullptr,
                                       sum1, sq1, buf);
    gemm_k<1,1><<<gg, bb, 0, stream>>>(buf, NN, 128, W2, b2,
                                       sum1, sq1, g1, be1,
                                       sum2, sq2, out);
    mega_k<<<gg, bb, 0, stream>>>(out, sum2, sq2, g2, be2, Wv, bv, Wo, bo, mask, out);
}

// Round 6
// 265.386 us; speedup vs baseline: 1.9565x; 1.2738x over previous
//
#include <hip/hip_runtime.h>

#define NN 50000
#define NE 800000
#define TOTF 114688   // frag elems: W1 (8kc*8nt*64*8=32768) + 5 matrices * 16384

typedef unsigned short u16;
typedef unsigned int u32;
typedef __attribute__((ext_vector_type(8))) short s8v;   // 8 bf16 = 4 VGPRs (MFMA A/B frag)
typedef __attribute__((ext_vector_type(4))) float f4v;   // MFMA C/D frag

// split fp32 into hi (truncated bf16) + lo (bf16 of remainder): f ~= hi + lo, err ~2^-16*|f|
__device__ __forceinline__ void split2(float f, u16& h, u16& lo) {
    u32 u = __float_as_uint(f);
    h = (u16)(u >> 16);
    float r = f - __uint_as_float(u & 0xFFFF0000u);   // exact
    lo = (u16)(__float_as_uint(r) >> 16);
}

// ---- in-degree mask scatter: mask[dst[e]] = 1 ----
__global__ void mask_scatter_k(const int* __restrict__ dst, float* __restrict__ mask) {
    int i = blockIdx.x * blockDim.x + threadIdx.x;
    if (i < NE) mask[dst[i]] = 1.0f;
}

// ---- convert the 6 weight matrices into B-fragment-ordered split-bf16 arrays ----
// frag layout: elem(idx): j=idx&7, l=(idx>>3)&63, nt=(idx>>9)&7, kc=idx>>12
//   maps to W[kc*32 + (l>>4)*8 + j][nt*16 + (l&15)]   (B[k][n]: k=quad*8+j, n=lane&15)
// matrix order/offsets: W1@0(32768) | W2@32768 | Wv0@49152 | Wo0@65536 | Wv1@81920 | Wo1@98304
__global__ void prep_w_k(const float* __restrict__ W1, const float* __restrict__ W2,
                         const float* __restrict__ Wv, const float* __restrict__ Wo,
                         u16* __restrict__ fh, u16* __restrict__ fl) {
    int idx = blockIdx.x * 256 + threadIdx.x;
    if (idx >= TOTF) return;
    const float* W;
    int local;
    if (idx < 32768) { W = W1; local = idx; }
    else {
        int t = idx - 32768;
        int m = t >> 14;
        local = t & 16383;
        if (m == 0) W = W2;
        else if (m == 1) W = Wv;
        else if (m == 2) W = Wo;
        else if (m == 3) W = Wv + 16384;
        else W = Wo + 16384;
    }
    int j = local & 7, l = (local >> 3) & 63, nt = (local >> 9) & 7, kc = local >> 12;
    int k = kc * 32 + ((l >> 4) << 3) + j;
    int n = nt * 16 + (l & 15);
    u16 h, lo;
    split2(W[k * 128 + n], h, lo);
    fh[idx] = h;
    fl[idx] = lo;
}

// ---- MFMA GEMM: C[M,128] = op_in(A[M,K]) @ W + bias, fused col stats ----
// wave w owns rows 16w..16w+15 of the 64-row block; split-bf16 (3 MFMA per tile).
template<int KC, int FOLD, int STATS>
__global__ __launch_bounds__(256)
void mgemm_k(const float* __restrict__ A,
             const u16* __restrict__ fh, const u16* __restrict__ fl,
             const float* __restrict__ bias,
             const float* __restrict__ fsum, const float* __restrict__ fsq,
             const float* __restrict__ fg, const float* __restrict__ fbe,
             float* __restrict__ osum, float* __restrict__ osq,
             float* __restrict__ C) {
    constexpr int K = KC * 32;
    __shared__ u16 Ah[64][K + 8];          // +8 elems (16B): row stride 16B-aligned, banks spread
    __shared__ u16 Al[64][K + 8];
    __shared__ float scl[128], shf[128], lsum[128], lsq[128];
    const int tid = threadIdx.x;
    const int l = tid & 63, w = tid >> 6;
    const int q = l >> 4, cc = l & 15;
    const int row0 = blockIdx.x * 64;

    if (FOLD && tid < 128) {
        float mean = fsum[tid] * (1.0f / NN);
        float var = fsq[tid] * (1.0f / NN) - mean * mean;   // biased
        float rstd = rsqrtf(var + 1e-5f);
        float ga = fg[tid] * rstd;
        scl[tid] = ga;
        shf[tid] = fbe[tid] - mean * ga;
    }
    if (STATS && tid < 128) { lsum[tid] = 0.f; lsq[tid] = 0.f; }
    __syncthreads();

    // wave-local staging: rows 16w..16w+15, fp32 -> (bn+relu) -> hi/lo planes
#pragma unroll
    for (int i = 0; i < K / 16; ++i) {
        int lin = i * 64 + l;
        int r16 = lin / (K / 4);
        int c4 = (lin % (K / 4)) * 4;
        int gr = row0 + 16 * w + r16; if (gr > NN - 1) gr = NN - 1;
        float4 f = *(const float4*)(A + (size_t)gr * K + c4);
        float v[4] = {f.x, f.y, f.z, f.w};
        if (FOLD) {
#pragma unroll
            for (int m = 0; m < 4; ++m) {
                float t = v[m] * scl[c4 + m] + shf[c4 + m];
                v[m] = t > 0.f ? t : 0.f;
            }
        }
        int rl = 16 * w + r16;
#pragma unroll
        for (int m = 0; m < 4; ++m) {
            u16 h, lo; split2(v[m], h, lo);
            Ah[rl][c4 + m] = h;
            Al[rl][c4 + m] = lo;
        }
    }
    // no barrier: each wave reads only rows it wrote (DS ops in-order per wave)

    f4v zf = {0.f, 0.f, 0.f, 0.f};
    f4v acc[8];
#pragma unroll
    for (int nt = 0; nt < 8; ++nt) acc[nt] = zf;

#pragma unroll
    for (int kc = 0; kc < KC; ++kc) {
        int ks = kc * 32 + q * 8;
        s8v ah = *(const s8v*)&Ah[16 * w + cc][ks];     // A[m=lane&15][k=quad*8+j]
        s8v al = *(const s8v*)&Al[16 * w + cc][ks];
#pragma unroll
        for (int nt = 0; nt < 8; ++nt) {
            const int fo = (((kc * 8 + nt) * 64) + l) * 8;
            s8v bh = *(const s8v*)(fh + fo);
            s8v bl = *(const s8v*)(fl + fo);
            acc[nt] = __builtin_amdgcn_mfma_f32_16x16x32_bf16(ah, bh, acc[nt], 0, 0, 0);
            acc[nt] = __builtin_amdgcn_mfma_f32_16x16x32_bf16(ah, bl, acc[nt], 0, 0, 0);
            acc[nt] = __builtin_amdgcn_mfma_f32_16x16x32_bf16(al, bh, acc[nt], 0, 0, 0);
        }
    }

    // epilogue: D[row=quad*4+r][col=lane&15] per 16-col tile; raw store + stats
    float ps[8], pq[8];
#pragma unroll
    for (int nt = 0; nt < 8; ++nt) { ps[nt] = 0.f; pq[nt] = 0.f; }
#pragma unroll
    for (int nt = 0; nt < 8; ++nt) {
        float bb = bias[nt * 16 + cc];
#pragma unroll
        for (int r = 0; r < 4; ++r) {
            int gr = row0 + 16 * w + q * 4 + r;
            float val = acc[nt][r] + bb;
            if (gr < NN) {
                C[(size_t)gr * 128 + nt * 16 + cc] = val;
                if (STATS) { ps[nt] += val; pq[nt] += val * val; }
            }
        }
    }
    if (STATS) {
#pragma unroll
        for (int nt = 0; nt < 8; ++nt) {
            ps[nt] += __shfl_xor(ps[nt], 16); ps[nt] += __shfl_xor(ps[nt], 32);
            pq[nt] += __shfl_xor(pq[nt], 16); pq[nt] += __shfl_xor(pq[nt], 32);
        }
        if (l < 16) {
#pragma unroll
            for (int nt = 0; nt < 8; ++nt) {
                atomicAdd(&lsum[nt * 16 + l], ps[nt]);
                atomicAdd(&lsq[nt * 16 + l], pq[nt]);
            }
        }
        __syncthreads();
        if (tid < 128) {
            atomicAdd(&osum[tid], lsum[tid]);
            atomicAdd(&osq[tid], lsq[tid]);
        }
    }
}

// ---- mega: bn2+relu -> (.@Wv0+bv0)*mask -> relu(.@Wo0+bo0) -> (.@Wv1+bv1)*mask
//            -> relu(.@Wo1+bo1) -> out.  Wave-local rows: ZERO barriers in stage loop.
__global__ __launch_bounds__(256)
void mmega_k(const float* __restrict__ X,
             const u16* __restrict__ fh, const u16* __restrict__ fl,   // Wv0 frag base
             const float* __restrict__ bv, const float* __restrict__ bo,
             const float* __restrict__ fsum, const float* __restrict__ fsq,
             const float* __restrict__ fg, const float* __restrict__ fbe,
             const float* __restrict__ mask, float* __restrict__ out) {
    __shared__ u16 Ah[64][136];
    __shared__ u16 Al[64][136];
    __shared__ float scl[128], shf[128];
    const int tid = threadIdx.x;
    const int l = tid & 63, w = tid >> 6;
    const int q = l >> 4, cc = l & 15;
    const int row0 = blockIdx.x * 64;

    if (tid < 128) {
        float mean = fsum[tid] * (1.0f / NN);
        float var = fsq[tid] * (1.0f / NN) - mean * mean;
        float rstd = rsqrtf(var + 1e-5f);
        float ga = fg[tid] * rstd;
        scl[tid] = ga;
        shf[tid] = fbe[tid] - mean * ga;
    }
    __syncthreads();

    float rm[4];
#pragma unroll
    for (int r = 0; r < 4; ++r) {
        int gr = row0 + 16 * w + q * 4 + r;
        rm[r] = (gr < NN) ? mask[gr] : 0.f;
    }

    // stage relu(bn2(X)) rows 16w..16w+15 into split planes
#pragma unroll
    for (int i = 0; i < 8; ++i) {
        int lin = i * 64 + l;
        int r16 = lin >> 5;
        int c4 = (lin & 31) * 4;
        int gr = row0 + 16 * w + r16; if (gr > NN - 1) gr = NN - 1;
        float4 f = *(const float4*)(X + (size_t)gr * 128 + c4);
        float v[4] = {f.x, f.y, f.z, f.w};
        int rl = 16 * w + r16;
#pragma unroll
        for (int m = 0; m < 4; ++m) {
            float t = v[m] * scl[c4 + m] + shf[c4 + m];
            t = t > 0.f ? t : 0.f;
            u16 h, lo; split2(t, h, lo);
            Ah[rl][c4 + m] = h;
            Al[rl][c4 + m] = lo;
        }
    }

    f4v zf = {0.f, 0.f, 0.f, 0.f};
    for (int s = 0; s < 4; ++s) {
        const u16* WH = fh + s * 16384;     // Wv0, Wo0, Wv1, Wo1 consecutive in frag buffer
        const u16* WL = fl + s * 16384;
        const float* bp = (s == 0) ? bv : (s == 1) ? bo : (s == 2) ? (bv + 128) : (bo + 128);

        f4v acc[8];
#pragma unroll
        for (int nt = 0; nt < 8; ++nt) acc[nt] = zf;
#pragma unroll
        for (int kc = 0; kc < 4; ++kc) {
            int ks = kc * 32 + q * 8;
            s8v ah = *(const s8v*)&Ah[16 * w + cc][ks];
            s8v al = *(const s8v*)&Al[16 * w + cc][ks];
#pragma unroll
            for (int nt = 0; nt < 8; ++nt) {
                const int fo = (((kc * 8 + nt) * 64) + l) * 8;
                s8v bh = *(const s8v*)(WH + fo);
                s8v bl = *(const s8v*)(WL + fo);
                acc[nt] = __builtin_amdgcn_mfma_f32_16x16x32_bf16(ah, bh, acc[nt], 0, 0, 0);
                acc[nt] = __builtin_amdgcn_mfma_f32_16x16x32_bf16(ah, bl, acc[nt], 0, 0, 0);
                acc[nt] = __builtin_amdgcn_mfma_f32_16x16x32_bf16(al, bh, acc[nt], 0, 0, 0);
            }
        }

        if (s == 3) {
#pragma unroll
            for (int nt = 0; nt < 8; ++nt) {
                float bb = bp[nt * 16 + cc];
#pragma unroll
                for (int r = 0; r < 4; ++r) {
                    int gr = row0 + 16 * w + q * 4 + r;
                    if (gr < NN)
                        out[(size_t)gr * 128 + nt * 16 + cc] = fmaxf(acc[nt][r] + bb, 0.f);
                }
            }
        } else {
            // all of this wave's reads (DS in-order) precede these writes; rows wave-local
#pragma unroll
            for (int nt = 0; nt < 8; ++nt) {
                float bb = bp[nt * 16 + cc];
#pragma unroll
                for (int r = 0; r < 4; ++r) {
                    int rl = 16 * w + q * 4 + r;
                    float val = acc[nt][r] + bb;
                    val = (s == 1) ? fmaxf(val, 0.f) : val * rm[r];
                    u16 h, lo; split2(val, h, lo);
                    Ah[rl][nt * 16 + cc] = h;
                    Al[rl][nt * 16 + cc] = lo;
                }
            }
        }
    }
}

extern "C" void kernel_launch(void* const* d_in, const int* in_sizes, int n_in,
                              void* d_out, int out_size, void* d_ws, size_t ws_size,
                              hipStream_t stream) {
    const float* x   = (const float*)d_in[0];
    const int*   ei  = (const int*)d_in[1];
    const float* W1  = (const float*)d_in[2];
    const float* b1  = (const float*)d_in[3];
    const float* g1  = (const float*)d_in[4];
    const float* be1 = (const float*)d_in[5];
    const float* W2  = (const float*)d_in[6];
    const float* b2  = (const float*)d_in[7];
    const float* g2  = (const float*)d_in[8];
    const float* be2 = (const float*)d_in[9];
    // Wq/bq (10,11), Wk/bk (12,13) cancel: V gathered at dst => segment softmax sums to 1.
    const float* Wv  = (const float*)d_in[14];
    const float* bv  = (const float*)d_in[15];
    const float* Wo  = (const float*)d_in[16];
    const float* bo  = (const float*)d_in[17];

    float* out = (float*)d_out;

    char* ws = (char*)d_ws;
    float* buf  = (float*)(ws);                    // 25.6 MB raw x@W1+b1
    float* mask = (float*)(ws + 25600000);         // 200 KB
    float* st   = (float*)(ws + 25800704);         // 2 KB stats
    u16*   fH   = (u16*)(ws + 25804800);           // 229 KB frag hi
    u16*   fL   = fH + TOTF;                       // 229 KB frag lo
    float *sum1 = st, *sq1 = st + 128, *sum2 = st + 256, *sq2 = st + 384;

    hipMemsetAsync(st, 0, 512 * sizeof(float), stream);
    hipMemsetAsync(mask, 0, NN * sizeof(float), stream);
    mask_scatter_k<<<dim3((NE + 255) / 256), dim3(256), 0, stream>>>(ei + NE, mask);
    prep_w_k<<<dim3((TOTF + 255) / 256), dim3(256), 0, stream>>>(W1, W2, Wv, Wo, fH, fL);

    dim3 gg((NN + 63) / 64), bb(256);
    // enc1: buf = x@W1+b1 (raw) + stats
    mgemm_k<8, 0, 1><<<gg, bb, 0, stream>>>(x, fH, fL, b1,
                                            nullptr, nullptr, nullptr, nullptr,
                                            sum1, sq1, buf);
    // enc2: out = relu(bn1(buf))@W2+b2 (raw) + stats
    mgemm_k<4, 1, 1><<<gg, bb, 0, stream>>>(buf, fH + 32768, fL + 32768, b2,
                                            sum1, sq1, g1, be1,
                                            sum2, sq2, out);
    // attention chain (collapsed), in-place on d_out
    mmega_k<<<gg, bb, 0, stream>>>(out, fH + 49152, fL + 49152, bv, bo,
                                   sum2, sq2, g2, be2, mask, out);
}

// Round 7
// 244.983 us; speedup vs baseline: 2.1194x; 1.0833x over previous
//
#include <hip/hip_runtime.h>

#define NN 50000
#define NE 800000
#define NB 782      // ceil(NN/64)
#define TOTF 114688 // frag elems: W1 (8kc*8nt*64*8=32768) + 5 matrices * 16384

typedef unsigned short u16;
typedef unsigned int u32;
typedef __attribute__((ext_vector_type(8))) short s8v;   // 8 bf16 = 4 VGPRs (MFMA A/B frag)
typedef __attribute__((ext_vector_type(4))) float f4v;   // MFMA C/D frag

// split fp32 into hi (truncated bf16) + lo (bf16 of remainder): f ~= hi + lo, err ~2^-16*|f|
__device__ __forceinline__ void split2(float f, u16& h, u16& lo) {
    u32 u = __float_as_uint(f);
    h = (u16)(u >> 16);
    float r = f - __uint_as_float(u & 0xFFFF0000u);   // exact
    lo = (u16)(__float_as_uint(r) >> 16);
}

// ---- in-degree mask scatter: mask[dst[e]] = 1 ----
__global__ void mask_scatter_k(const int* __restrict__ dst, float* __restrict__ mask) {
    int i = blockIdx.x * blockDim.x + threadIdx.x;
    if (i < NE) mask[dst[i]] = 1.0f;
}

// ---- convert the 6 weight matrices into B-fragment-ordered split-bf16 arrays ----
// frag elem(idx): j=idx&7, l=(idx>>3)&63, nt=(idx>>9)&7, kc=idx>>12
//   -> W[kc*32 + (l>>4)*8 + j][nt*16 + (l&15)]
__global__ void prep_w_k(const float* __restrict__ W1, const float* __restrict__ W2,
                         const float* __restrict__ Wv, const float* __restrict__ Wo,
                         u16* __restrict__ fh, u16* __restrict__ fl) {
    int idx = blockIdx.x * 256 + threadIdx.x;
    if (idx >= TOTF) return;
    const float* W;
    int local;
    if (idx < 32768) { W = W1; local = idx; }
    else {
        int t = idx - 32768;
        int m = t >> 14;
        local = t & 16383;
        if (m == 0) W = W2;
        else if (m == 1) W = Wv;
        else if (m == 2) W = Wo;
        else if (m == 3) W = Wv + 16384;
        else W = Wo + 16384;
    }
    int j = local & 7, l = (local >> 3) & 63, nt = (local >> 9) & 7, kc = local >> 12;
    int k = kc * 32 + ((l >> 4) << 3) + j;
    int n = nt * 16 + (l & 15);
    u16 h, lo;
    split2(W[k * 128 + n], h, lo);
    fh[idx] = h;
    fl[idx] = lo;
}

// ---- reduce per-block stat partials: st[c] = sum_b pst[b][c], c in [0,256) ----
__global__ __launch_bounds__(64)
void redstats_k(const float* __restrict__ pst, float* __restrict__ st) {
    int c = blockIdx.x;
    float s = 0.f;
    for (int b = threadIdx.x; b < NB; b += 64) s += pst[(size_t)b * 256 + c];
    s += __shfl_xor(s, 1);  s += __shfl_xor(s, 2);  s += __shfl_xor(s, 4);
    s += __shfl_xor(s, 8);  s += __shfl_xor(s, 16); s += __shfl_xor(s, 32);
    if (threadIdx.x == 0) st[c] = s;
}

// ---- MFMA GEMM: C[M,128] = op_in(A[M,K]) @ W + bias; per-block stat partials ----
// wave w owns rows 16w..16w+15 of the 64-row block; split-bf16 (3 MFMA per tile).
template<int KC, int FOLD, int STATS>
__global__ __launch_bounds__(256)
void mgemm_k(const float* __restrict__ A,
             const u16* __restrict__ fh, const u16* __restrict__ fl,
             const float* __restrict__ bias,
             const float* __restrict__ fst,        // prev-layer stats [256] (sum|sq)
             const float* __restrict__ fg, const float* __restrict__ fbe,
             float* __restrict__ pst,              // per-block partials [NB][256]
             float* __restrict__ C) {
    constexpr int K = KC * 32;
    __shared__ u16 Ah[64][K + 8];
    __shared__ u16 Al[64][K + 8];
    __shared__ float scl[128], shf[128];
    __shared__ float wsum[4][128], wsq[4][128];
    const int tid = threadIdx.x;
    const int l = tid & 63, w = tid >> 6;
    const int q = l >> 4, cc = l & 15;
    const int row0 = blockIdx.x * 64;

    if (FOLD && tid < 128) {
        float mean = fst[tid] * (1.0f / NN);
        float var = fst[128 + tid] * (1.0f / NN) - mean * mean;   // biased
        float rstd = rsqrtf(var + 1e-5f);
        float ga = fg[tid] * rstd;
        scl[tid] = ga;
        shf[tid] = fbe[tid] - mean * ga;
    }
    if (FOLD) __syncthreads();

    // wave-local staging: rows 16w..16w+15, fp32 -> (bn+relu) -> hi/lo planes
#pragma unroll
    for (int i = 0; i < K / 16; ++i) {
        int lin = i * 64 + l;
        int r16 = lin / (K / 4);
        int c4 = (lin % (K / 4)) * 4;
        int gr = row0 + 16 * w + r16; if (gr > NN - 1) gr = NN - 1;
        float4 f = *(const float4*)(A + (size_t)gr * K + c4);
        float v[4] = {f.x, f.y, f.z, f.w};
        if (FOLD) {
#pragma unroll
            for (int m = 0; m < 4; ++m) {
                float t = v[m] * scl[c4 + m] + shf[c4 + m];
                v[m] = t > 0.f ? t : 0.f;
            }
        }
        int rl = 16 * w + r16;
#pragma unroll
        for (int m = 0; m < 4; ++m) {
            u16 h, lo; split2(v[m], h, lo);
            Ah[rl][c4 + m] = h;
            Al[rl][c4 + m] = lo;
        }
    }
    // no barrier: each wave reads only rows it wrote (DS ops in-order per wave)

    f4v zf = {0.f, 0.f, 0.f, 0.f};
    f4v acc[8];
#pragma unroll
    for (int nt = 0; nt < 8; ++nt) acc[nt] = zf;

#pragma unroll
    for (int kc = 0; kc < KC; ++kc) {
        int ks = kc * 32 + q * 8;
        s8v ah = *(const s8v*)&Ah[16 * w + cc][ks];     // A[m=lane&15][k=quad*8+j]
        s8v al = *(const s8v*)&Al[16 * w + cc][ks];
#pragma unroll
        for (int nt = 0; nt < 8; ++nt) {
            const int fo = (((kc * 8 + nt) * 64) + l) * 8;
            s8v bh = *(const s8v*)(fh + fo);
            s8v bl = *(const s8v*)(fl + fo);
            acc[nt] = __builtin_amdgcn_mfma_f32_16x16x32_bf16(ah, bh, acc[nt], 0, 0, 0);
            acc[nt] = __builtin_amdgcn_mfma_f32_16x16x32_bf16(ah, bl, acc[nt], 0, 0, 0);
            acc[nt] = __builtin_amdgcn_mfma_f32_16x16x32_bf16(al, bh, acc[nt], 0, 0, 0);
        }
    }

    // epilogue: D[row=quad*4+r][col=lane&15] per 16-col tile; raw store + stat partials
    float ps[8], pq[8];
#pragma unroll
    for (int nt = 0; nt < 8; ++nt) { ps[nt] = 0.f; pq[nt] = 0.f; }
#pragma unroll
    for (int nt = 0; nt < 8; ++nt) {
        float bb = bias[nt * 16 + cc];
#pragma unroll
        for (int r = 0; r < 4; ++r) {
            int gr = row0 + 16 * w + q * 4 + r;
            float val = acc[nt][r] + bb;
            if (gr < NN) {
                C[(size_t)gr * 128 + nt * 16 + cc] = val;
                if (STATS) { ps[nt] += val; pq[nt] += val * val; }
            }
        }
    }
    if (STATS) {
        // reduce row-groups within the wave; lanes 0..15 hold 8 column-partials each
#pragma unroll
        for (int nt = 0; nt < 8; ++nt) {
            ps[nt] += __shfl_xor(ps[nt], 16); ps[nt] += __shfl_xor(ps[nt], 32);
            pq[nt] += __shfl_xor(pq[nt], 16); pq[nt] += __shfl_xor(pq[nt], 32);
        }
        if (l < 16) {
#pragma unroll
            for (int nt = 0; nt < 8; ++nt) {
                wsum[w][nt * 16 + l] = ps[nt];
                wsq[w][nt * 16 + l] = pq[nt];
            }
        }
        __syncthreads();
        // one coalesced 1KB record per block — NO atomics anywhere
        if (tid < 128) {
            pst[(size_t)blockIdx.x * 256 + tid] =
                wsum[0][tid] + wsum[1][tid] + wsum[2][tid] + wsum[3][tid];
        } else {
            int c = tid - 128;
            pst[(size_t)blockIdx.x * 256 + tid] =
                wsq[0][c] + wsq[1][c] + wsq[2][c] + wsq[3][c];
        }
    }
}

// ---- mega: bn2+relu -> (.@Wv0+bv0)*mask -> relu(.@Wo0+bo0) -> (.@Wv1+bv1)*mask
//            -> relu(.@Wo1+bo1) -> out.  Wave-local rows: zero barriers in stage loop.
__global__ __launch_bounds__(256)
void mmega_k(const float* __restrict__ X,
             const u16* __restrict__ fh, const u16* __restrict__ fl,   // Wv0 frag base
             const float* __restrict__ bv, const float* __restrict__ bo,
             const float* __restrict__ fst,
             const float* __restrict__ fg, const float* __restrict__ fbe,
             const float* __restrict__ mask, float* __restrict__ out) {
    __shared__ u16 Ah[64][136];
    __shared__ u16 Al[64][136];
    __shared__ float scl[128], shf[128];
    const int tid = threadIdx.x;
    const int l = tid & 63, w = tid >> 6;
    const int q = l >> 4, cc = l & 15;
    const int row0 = blockIdx.x * 64;

    if (tid < 128) {
        float mean = fst[tid] * (1.0f / NN);
        float var = fst[128 + tid] * (1.0f / NN) - mean * mean;
        float rstd = rsqrtf(var + 1e-5f);
        float ga = fg[tid] * rstd;
        scl[tid] = ga;
        shf[tid] = fbe[tid] - mean * ga;
    }
    __syncthreads();

    float rm[4];
#pragma unroll
    for (int r = 0; r < 4; ++r) {
        int gr = row0 + 16 * w + q * 4 + r;
        rm[r] = (gr < NN) ? mask[gr] : 0.f;
    }

    // stage relu(bn2(X)) rows 16w..16w+15 into split planes
#pragma unroll
    for (int i = 0; i < 8; ++i) {
        int lin = i * 64 + l;
        int r16 = lin >> 5;
        int c4 = (lin & 31) * 4;
        int gr = row0 + 16 * w + r16; if (gr > NN - 1) gr = NN - 1;
        float4 f = *(const float4*)(X + (size_t)gr * 128 + c4);
        float v[4] = {f.x, f.y, f.z, f.w};
        int rl = 16 * w + r16;
#pragma unroll
        for (int m = 0; m < 4; ++m) {
            float t = v[m] * scl[c4 + m] + shf[c4 + m];
            t = t > 0.f ? t : 0.f;
            u16 h, lo; split2(t, h, lo);
            Ah[rl][c4 + m] = h;
            Al[rl][c4 + m] = lo;
        }
    }

    f4v zf = {0.f, 0.f, 0.f, 0.f};
    for (int s = 0; s < 4; ++s) {
        const u16* WH = fh + s * 16384;     // Wv0, Wo0, Wv1, Wo1 consecutive
        const u16* WL = fl + s * 16384;
        const float* bp = (s == 0) ? bv : (s == 1) ? bo : (s == 2) ? (bv + 128) : (bo + 128);

        f4v acc[8];
#pragma unroll
        for (int nt = 0; nt < 8; ++nt) acc[nt] = zf;
#pragma unroll
        for (int kc = 0; kc < 4; ++kc) {
            int ks = kc * 32 + q * 8;
            s8v ah = *(const s8v*)&Ah[16 * w + cc][ks];
            s8v al = *(const s8v*)&Al[16 * w + cc][ks];
#pragma unroll
            for (int nt = 0; nt < 8; ++nt) {
                const int fo = (((kc * 8 + nt) * 64) + l) * 8;
                s8v bh = *(const s8v*)(WH + fo);
                s8v bl = *(const s8v*)(WL + fo);
                acc[nt] = __builtin_amdgcn_mfma_f32_16x16x32_bf16(ah, bh, acc[nt], 0, 0, 0);
                acc[nt] = __builtin_amdgcn_mfma_f32_16x16x32_bf16(ah, bl, acc[nt], 0, 0, 0);
                acc[nt] = __builtin_amdgcn_mfma_f32_16x16x32_bf16(al, bh, acc[nt], 0, 0, 0);
            }
        }

        if (s == 3) {
#pragma unroll
            for (int nt = 0; nt < 8; ++nt) {
                float bb = bp[nt * 16 + cc];
#pragma unroll
                for (int r = 0; r < 4; ++r) {
                    int gr = row0 + 16 * w + q * 4 + r;
                    if (gr < NN)
                        out[(size_t)gr * 128 + nt * 16 + cc] = fmaxf(acc[nt][r] + bb, 0.f);
                }
            }
        } else {
            // wave-local rows: this wave's DS reads (in-order) precede these writes
#pragma unroll
            for (int nt = 0; nt < 8; ++nt) {
                float bb = bp[nt * 16 + cc];
#pragma unroll
                for (int r = 0; r < 4; ++r) {
                    int rl = 16 * w + q * 4 + r;
                    float val = acc[nt][r] + bb;
                    val = (s == 1) ? fmaxf(val, 0.f) : val * rm[r];
                    u16 h, lo; split2(val, h, lo);
                    Ah[rl][nt * 16 + cc] = h;
                    Al[rl][nt * 16 + cc] = lo;
                }
            }
        }
    }
}

extern "C" void kernel_launch(void* const* d_in, const int* in_sizes, int n_in,
                              void* d_out, int out_size, void* d_ws, size_t ws_size,
                              hipStream_t stream) {
    const float* x   = (const float*)d_in[0];
    const int*   ei  = (const int*)d_in[1];
    const float* W1  = (const float*)d_in[2];
    const float* b1  = (const float*)d_in[3];
    const float* g1  = (const float*)d_in[4];
    const float* be1 = (const float*)d_in[5];
    const float* W2  = (const float*)d_in[6];
    const float* b2  = (const float*)d_in[7];
    const float* g2  = (const float*)d_in[8];
    const float* be2 = (const float*)d_in[9];
    // Wq/bq (10,11), Wk/bk (12,13) cancel: V gathered at dst => segment softmax sums to 1.
    const float* Wv  = (const float*)d_in[14];
    const float* bv  = (const float*)d_in[15];
    const float* Wo  = (const float*)d_in[16];
    const float* bo  = (const float*)d_in[17];

    float* out = (float*)d_out;

    char* ws = (char*)d_ws;
    float* buf  = (float*)(ws);                    // 25.6 MB raw x@W1+b1
    float* mask = (float*)(ws + 25600000);         // 200 KB
    float* st1  = (float*)(ws + 25800704);         // 1 KB  (sum|sq layer1)
    float* st2  = st1 + 256;                       // 1 KB  (layer2)
    u16*   fH   = (u16*)(ws + 25804800);           // 229 KB frag hi
    u16*   fL   = fH + TOTF;                       // 229 KB frag lo
    float* pst  = (float*)(ws + 26263552);         // NB*256*4 = 800 KB partials (reused)

    hipMemsetAsync(mask, 0, NN * sizeof(float), stream);
    mask_scatter_k<<<dim3((NE + 255) / 256), dim3(256), 0, stream>>>(ei + NE, mask);
    prep_w_k<<<dim3((TOTF + 255) / 256), dim3(256), 0, stream>>>(W1, W2, Wv, Wo, fH, fL);

    dim3 gg(NB), bb(256);
    // enc1: buf = x@W1+b1 (raw) + stat partials
    mgemm_k<8, 0, 1><<<gg, bb, 0, stream>>>(x, fH, fL, b1,
                                            nullptr, nullptr, nullptr, pst, buf);
    redstats_k<<<dim3(256), dim3(64), 0, stream>>>(pst, st1);
    // enc2: out = relu(bn1(buf))@W2+b2 (raw) + stat partials
    mgemm_k<4, 1, 1><<<gg, bb, 0, stream>>>(buf, fH + 32768, fL + 32768, b2,
                                            st1, g1, be1, pst, out);
    redstats_k<<<dim3(256), dim3(64), 0, stream>>>(pst, st2);
    // attention chain (collapsed), in-place on d_out
    mmega_k<<<gg, bb, 0, stream>>>(out, fH + 49152, fL + 49152, bv, bo,
                                   st2, g2, be2, mask, out);
}

// Round 8
// 227.283 us; speedup vs baseline: 2.2844x; 1.0779x over previous
//
#include <hip/hip_runtime.h>

#define NN 50000
#define NE 800000
#define NB 782      // ceil(NN/64)
#define TOTF 114688 // frag elems: W1 (8kc*8nt*64*8=32768) + 5 matrices * 16384

typedef unsigned short u16;
typedef unsigned int u32;
typedef __attribute__((ext_vector_type(8))) short s8v;   // 8 bf16 = 4 VGPRs (MFMA A/B frag)
typedef __attribute__((ext_vector_type(4))) float f4v;   // MFMA C/D frag

// split fp32 into hi (truncated bf16) + lo (bf16 of remainder): f ~= hi + lo, err ~2^-16*|f|
__device__ __forceinline__ void split2(float f, u16& h, u16& lo) {
    u32 u = __float_as_uint(f);
    h = (u16)(u >> 16);
    float r = f - __uint_as_float(u & 0xFFFF0000u);   // exact
    lo = (u16)(__float_as_uint(r) >> 16);
}

// ---- in-degree mask scatter: mask[dst[e]] = 1 ----
__global__ void mask_scatter_k(const int* __restrict__ dst, float* __restrict__ mask) {
    int i = blockIdx.x * blockDim.x + threadIdx.x;
    if (i < NE) mask[dst[i]] = 1.0f;
}

// ---- convert the 6 weight matrices into B-fragment-ordered split-bf16 arrays ----
// frag elem(idx): j=idx&7, l=(idx>>3)&63, nt=(idx>>9)&7, kc=idx>>12
//   -> W[kc*32 + (l>>4)*8 + j][nt*16 + (l&15)]
__global__ void prep_w_k(const float* __restrict__ W1, const float* __restrict__ W2,
                         const float* __restrict__ Wv, const float* __restrict__ Wo,
                         u16* __restrict__ fh, u16* __restrict__ fl) {
    int idx = blockIdx.x * 256 + threadIdx.x;
    if (idx >= TOTF) return;
    const float* W;
    int local;
    if (idx < 32768) { W = W1; local = idx; }
    else {
        int t = idx - 32768;
        int m = t >> 14;
        local = t & 16383;
        if (m == 0) W = W2;
        else if (m == 1) W = Wv;
        else if (m == 2) W = Wo;
        else if (m == 3) W = Wv + 16384;
        else W = Wo + 16384;
    }
    int j = local & 7, l = (local >> 3) & 63, nt = (local >> 9) & 7, kc = local >> 12;
    int k = kc * 32 + ((l >> 4) << 3) + j;
    int n = nt * 16 + (l & 15);
    u16 h, lo;
    split2(W[k * 128 + n], h, lo);
    fh[idx] = h;
    fl[idx] = lo;
}

// ---- reduce per-block stat partials: st[c] = sum_b pst[b][c], c in [0,256) ----
__global__ __launch_bounds__(64)
void redstats_k(const float* __restrict__ pst, float* __restrict__ st) {
    int c = blockIdx.x;
    float s = 0.f;
    for (int b = threadIdx.x; b < NB; b += 64) s += pst[(size_t)b * 256 + c];
    s += __shfl_xor(s, 1);  s += __shfl_xor(s, 2);  s += __shfl_xor(s, 4);
    s += __shfl_xor(s, 8);  s += __shfl_xor(s, 16); s += __shfl_xor(s, 32);
    if (threadIdx.x == 0) st[c] = s;
}

// ---- MFMA GEMM, 8-wave blocks: 64 rows, waves pair up per 16-row slice, 4 nt each ----
// K processed in passes of 128 (KP = KC/4) through a 64x136 split-bf16 LDS tile.
template<int KC, int FOLD, int STATS>
__global__ __launch_bounds__(512, 6)
void mgemm_k(const float* __restrict__ A,
             const u16* __restrict__ fh, const u16* __restrict__ fl,
             const float* __restrict__ bias,
             const float* __restrict__ fst,        // prev-layer stats [256] (sum|sq)
             const float* __restrict__ fg, const float* __restrict__ fbe,
             float* __restrict__ pst,              // per-block partials [NB][256]
             float* __restrict__ C) {
    constexpr int KP = KC / 4;       // 128-wide K passes
    __shared__ __align__(16) u16 Ah[64][136];
    __shared__ __align__(16) u16 Al[64][136];
    __shared__ float scl[128], shf[128];
    const int tid = threadIdx.x;
    const int l = tid & 63, w = tid >> 6;
    const int q = l >> 4, cc = l & 15;
    const int sl = w >> 1, hf = w & 1;           // slice 0..3, n-half 0..1
    const int row0 = blockIdx.x * 64;

    if (FOLD && tid < 128) {
        float mean = fst[tid] * (1.0f / NN);
        float var = fst[128 + tid] * (1.0f / NN) - mean * mean;   // biased
        float rstd = rsqrtf(var + 1e-5f);
        float ga = fg[tid] * rstd;
        scl[tid] = ga;
        shf[tid] = fbe[tid] - mean * ga;
    }

    f4v zf = {0.f, 0.f, 0.f, 0.f};
    f4v acc[4];
#pragma unroll
    for (int t = 0; t < 4; ++t) acc[t] = zf;

    for (int p = 0; p < KP; ++p) {
        if (p > 0 || FOLD) __syncthreads();      // prev-pass reads done / scl ready
        // cooperative staging: 64 rows x 128 k, fp32 -> (bn+relu) -> hi/lo planes
#pragma unroll
        for (int it = 0; it < 4; ++it) {
            int lin = tid + 512 * it;            // 0..2047
            int r = lin >> 5;
            int c4 = (lin & 31) * 4;
            int gr = row0 + r; if (gr > NN - 1) gr = NN - 1;
            float4 f = *(const float4*)(A + (size_t)gr * (KC * 32) + p * 128 + c4);
            float v[4] = {f.x, f.y, f.z, f.w};
            if (FOLD) {
#pragma unroll
                for (int m = 0; m < 4; ++m) {
                    float t = v[m] * scl[c4 + m] + shf[c4 + m];
                    v[m] = t > 0.f ? t : 0.f;
                }
            }
            ushort4 uh, ul;
            split2(v[0], uh.x, ul.x); split2(v[1], uh.y, ul.y);
            split2(v[2], uh.z, ul.z); split2(v[3], uh.w, ul.w);
            *(ushort4*)&Ah[r][c4] = uh;
            *(ushort4*)&Al[r][c4] = ul;
        }
        __syncthreads();
#pragma unroll
        for (int kc = 0; kc < 4; ++kc) {
            int kcg = p * 4 + kc;
            s8v ah = *(const s8v*)&Ah[16 * sl + cc][kc * 32 + q * 8];
            s8v al = *(const s8v*)&Al[16 * sl + cc][kc * 32 + q * 8];
#pragma unroll
            for (int t = 0; t < 4; ++t) {
                const int fo = kcg * 4096 + (4 * hf + t) * 512 + l * 8;
                s8v bh = *(const s8v*)(fh + fo);
                s8v bl = *(const s8v*)(fl + fo);
                acc[t] = __builtin_amdgcn_mfma_f32_16x16x32_bf16(ah, bh, acc[t], 0, 0, 0);
                acc[t] = __builtin_amdgcn_mfma_f32_16x16x32_bf16(ah, bl, acc[t], 0, 0, 0);
                acc[t] = __builtin_amdgcn_mfma_f32_16x16x32_bf16(al, bh, acc[t], 0, 0, 0);
            }
        }
    }

    // epilogue: D[row=16sl+q*4+r][col=(4hf+t)*16+cc]; raw store + stat partials
    float ps[4], pq[4];
#pragma unroll
    for (int t = 0; t < 4; ++t) { ps[t] = 0.f; pq[t] = 0.f; }
#pragma unroll
    for (int t = 0; t < 4; ++t) {
        int col = (4 * hf + t) * 16 + cc;
        float bb = bias[col];
#pragma unroll
        for (int r = 0; r < 4; ++r) {
            int gr = row0 + 16 * sl + q * 4 + r;
            float val = acc[t][r] + bb;
            if (gr < NN) {
                C[(size_t)gr * 128 + col] = val;
                if (STATS) { ps[t] += val; pq[t] += val * val; }
            }
        }
    }
    if (STATS) {
        __syncthreads();                          // all LDS reads done: reuse Ah as wred
        float* wredS = (float*)&Ah[0][0];         // [4][128]
        float* wredQ = wredS + 512;               // [4][128]
#pragma unroll
        for (int t = 0; t < 4; ++t) {
            ps[t] += __shfl_xor(ps[t], 16); ps[t] += __shfl_xor(ps[t], 32);
            pq[t] += __shfl_xor(pq[t], 16); pq[t] += __shfl_xor(pq[t], 32);
        }
        if (l < 16) {
#pragma unroll
            for (int t = 0; t < 4; ++t) {
                int col = (4 * hf + t) * 16 + l;
                wredS[sl * 128 + col] = ps[t];
                wredQ[sl * 128 + col] = pq[t];
            }
        }
        __syncthreads();
        if (tid < 256) {                          // one coalesced 1KB record per block
            int c = tid & 127;
            const float* src = (tid < 128) ? wredS : wredQ;
            pst[(size_t)blockIdx.x * 256 + tid] =
                src[c] + src[128 + c] + src[256 + c] + src[384 + c];
        }
    }
}

// ---- mega: bn2+relu -> (.@Wv0+bv0)*mask -> relu(.@Wo0+bo0) -> (.@Wv1+bv1)*mask
//            -> relu(.@Wo1+bo1) -> out.  8 waves; partner waves share a 16-row slice.
__global__ __launch_bounds__(512, 6)
void mmega_k(const float* __restrict__ X,
             const u16* __restrict__ fh, const u16* __restrict__ fl,   // Wv0 frag base
             const float* __restrict__ bv, const float* __restrict__ bo,
             const float* __restrict__ fst,
             const float* __restrict__ fg, const float* __restrict__ fbe,
             const float* __restrict__ mask, float* __restrict__ out) {
    __shared__ __align__(16) u16 Ah[64][136];
    __shared__ __align__(16) u16 Al[64][136];
    __shared__ float scl[128], shf[128];
    const int tid = threadIdx.x;
    const int l = tid & 63, w = tid >> 6;
    const int q = l >> 4, cc = l & 15;
    const int sl = w >> 1, hf = w & 1;
    const int row0 = blockIdx.x * 64;

    if (tid < 128) {
        float mean = fst[tid] * (1.0f / NN);
        float var = fst[128 + tid] * (1.0f / NN) - mean * mean;
        float rstd = rsqrtf(var + 1e-5f);
        float ga = fg[tid] * rstd;
        scl[tid] = ga;
        shf[tid] = fbe[tid] - mean * ga;
    }
    __syncthreads();

    float rm[4];
#pragma unroll
    for (int r = 0; r < 4; ++r) {
        int gr = row0 + 16 * sl + q * 4 + r;
        rm[r] = (gr < NN) ? mask[gr] : 0.f;
    }

    // stage relu(bn2(X)) into split planes (cooperative, 64 rows x 128 k)
#pragma unroll
    for (int it = 0; it < 4; ++it) {
        int lin = tid + 512 * it;
        int r = lin >> 5;
        int c4 = (lin & 31) * 4;
        int gr = row0 + r; if (gr > NN - 1) gr = NN - 1;
        float4 f = *(const float4*)(X + (size_t)gr * 128 + c4);
        float v[4] = {f.x, f.y, f.z, f.w};
        ushort4 uh, ul;
#pragma unroll
        for (int m = 0; m < 4; ++m) {
            float t = v[m] * scl[c4 + m] + shf[c4 + m];
            v[m] = t > 0.f ? t : 0.f;
        }
        split2(v[0], uh.x, ul.x); split2(v[1], uh.y, ul.y);
        split2(v[2], uh.z, ul.z); split2(v[3], uh.w, ul.w);
        *(ushort4*)&Ah[r][c4] = uh;
        *(ushort4*)&Al[r][c4] = ul;
    }
    __syncthreads();

    f4v zf = {0.f, 0.f, 0.f, 0.f};
    for (int s = 0; s < 4; ++s) {
        const u16* WH = fh + s * 16384;     // Wv0, Wo0, Wv1, Wo1 consecutive
        const u16* WL = fl + s * 16384;
        const float* bp = (s == 0) ? bv : (s == 1) ? bo : (s == 2) ? (bv + 128) : (bo + 128);

        f4v acc[4];
#pragma unroll
        for (int t = 0; t < 4; ++t) acc[t] = zf;
#pragma unroll
        for (int kc = 0; kc < 4; ++kc) {
            s8v ah = *(const s8v*)&Ah[16 * sl + cc][kc * 32 + q * 8];
            s8v al = *(const s8v*)&Al[16 * sl + cc][kc * 32 + q * 8];
#pragma unroll
            for (int t = 0; t < 4; ++t) {
                const int fo = kc * 4096 + (4 * hf + t) * 512 + l * 8;
                s8v bh = *(const s8v*)(WH + fo);
                s8v bl = *(const s8v*)(WL + fo);
                acc[t] = __builtin_amdgcn_mfma_f32_16x16x32_bf16(ah, bh, acc[t], 0, 0, 0);
                acc[t] = __builtin_amdgcn_mfma_f32_16x16x32_bf16(ah, bl, acc[t], 0, 0, 0);
                acc[t] = __builtin_amdgcn_mfma_f32_16x16x32_bf16(al, bh, acc[t], 0, 0, 0);
            }
        }

        if (s == 3) {
#pragma unroll
            for (int t = 0; t < 4; ++t) {
                int col = (4 * hf + t) * 16 + cc;
                float bb = bp[col];
#pragma unroll
                for (int r = 0; r < 4; ++r) {
                    int gr = row0 + 16 * sl + q * 4 + r;
                    if (gr < NN)
                        out[(size_t)gr * 128 + col] = fmaxf(acc[t][r] + bb, 0.f);
                }
            }
        } else {
            __syncthreads();    // partner wave's reads of this slice done before overwrite
#pragma unroll
            for (int t = 0; t < 4; ++t) {
                int col = (4 * hf + t) * 16 + cc;
                float bb = bp[col];
#pragma unroll
                for (int r = 0; r < 4; ++r) {
                    int rl = 16 * sl + q * 4 + r;
                    float val = acc[t][r] + bb;
                    val = (s == 1) ? fmaxf(val, 0.f) : val * rm[r];
                    u16 h, lo; split2(val, h, lo);
                    Ah[rl][col] = h;
                    Al[rl][col] = lo;
                }
            }
            __syncthreads();    // writes visible before next stage's reads
        }
    }
}

extern "C" void kernel_launch(void* const* d_in, const int* in_sizes, int n_in,
                              void* d_out, int out_size, void* d_ws, size_t ws_size,
                              hipStream_t stream) {
    const float* x   = (const float*)d_in[0];
    const int*   ei  = (const int*)d_in[1];
    const float* W1  = (const float*)d_in[2];
    const float* b1  = (const float*)d_in[3];
    const float* g1  = (const float*)d_in[4];
    const float* be1 = (const float*)d_in[5];
    const float* W2  = (const float*)d_in[6];
    const float* b2  = (const float*)d_in[7];
    const float* g2  = (const float*)d_in[8];
    const float* be2 = (const float*)d_in[9];
    // Wq/bq (10,11), Wk/bk (12,13) cancel: V gathered at dst => segment softmax sums to 1.
    const float* Wv  = (const float*)d_in[14];
    const float* bv  = (const float*)d_in[15];
    const float* Wo  = (const float*)d_in[16];
    const float* bo  = (const float*)d_in[17];

    float* out = (float*)d_out;

    char* ws = (char*)d_ws;
    float* buf  = (float*)(ws);                    // 25.6 MB raw x@W1+b1
    float* mask = (float*)(ws + 25600000);         // 200 KB
    float* st1  = (float*)(ws + 25800704);         // 1 KB (sum|sq layer1)
    float* st2  = st1 + 256;                       // 1 KB (layer2)
    u16*   fH   = (u16*)(ws + 25804800);           // 229 KB frag hi
    u16*   fL   = fH + TOTF;                       // 229 KB frag lo
    float* pst  = (float*)(ws + 26263552);         // NB*256*4 = 800 KB partials (reused)

    hipMemsetAsync(mask, 0, NN * sizeof(float), stream);
    mask_scatter_k<<<dim3((NE + 255) / 256), dim3(256), 0, stream>>>(ei + NE, mask);
    prep_w_k<<<dim3((TOTF + 255) / 256), dim3(256), 0, stream>>>(W1, W2, Wv, Wo, fH, fL);

    dim3 gg(NB), bb(512);
    // enc1: buf = x@W1+b1 (raw) + stat partials
    mgemm_k<8, 0, 1><<<gg, bb, 0, stream>>>(x, fH, fL, b1,
                                            nullptr, nullptr, nullptr, pst, buf);
    redstats_k<<<dim3(256), dim3(64), 0, stream>>>(pst, st1);
    // enc2: out = relu(bn1(buf))@W2+b2 (raw) + stat partials
    mgemm_k<4, 1, 1><<<gg, bb, 0, stream>>>(buf, fH + 32768, fL + 32768, b2,
                                            st1, g1, be1, pst, out);
    redstats_k<<<dim3(256), dim3(64), 0, stream>>>(pst, st2);
    // attention chain (collapsed), in-place on d_out
    mmega_k<<<gg, bb, 0, stream>>>(out, fH + 49152, fL + 49152, bv, bo,
                                   st2, g2, be2, mask, out);
}